// Round 9
// baseline (336.068 us; speedup 1.0000x reference)
//
#include <hip/hip_runtime.h>
#include <hip/hip_fp16.h>

// 3-layer gather-GEMM GNN (N=262144, K=8, 16->128->128->16), f16 MFMA.
// Round 9: L1 LDS layout changed to seg-major + XOR swizzle
//   offset16(seg,row) = seg*64 + (row&~15) + ((row^seg)&15)
// -> both ds_write_b128 (staging) and ds_read_b128 (fragments) are 2-way max
// (free), killing the 8.4M conflict cycles of round 8's +8-half pad (which
// made row stride = 4 banks -> 8-way read aliasing). LDS 32 KB exact -> 5
// blocks/CU (was ~3), more gather concurrency.
// L0/L2 unchanged. Scaled messages prescaled by 2^-8; epilogue x256 + bias.
//
// Workspace: ws holds ONLY h1+h2 (128 MiB exactly). invd/h16/shuffled-W live
// in d_out (scratch until layer 2 overwrites it); layer 2's invd+Wf2 are
// d2d-copied into the dead h1 region first.

typedef _Float16 f16x8 __attribute__((ext_vector_type(8)));
typedef float f32x4 __attribute__((ext_vector_type(4)));

#define NNODES 262144

__global__ __launch_bounds__(256) void conv_h_kernel(const float* __restrict__ h,
                                                     __half* __restrict__ h16, int n) {
    int i = blockIdx.x * 256 + threadIdx.x;
    if (i < n) h16[i] = __float2half(h[i]);
}

__global__ __launch_bounds__(256) void prep_edges_kernel(const float* __restrict__ pos,
                                                         const int* __restrict__ nbr,
                                                         __half* __restrict__ invd, int n_edges) {
    int e = blockIdx.x * 256 + threadIdx.x;
    if (e >= n_edges) return;
    int i = e >> 3;
    int n = nbr[e];
    float dx = pos[i * 3 + 0] - pos[n * 3 + 0];
    float dy = pos[i * 3 + 1] - pos[n * 3 + 1];
    float dz = pos[i * 3 + 2] - pos[n * 3 + 2];
    float d = sqrtf(dx * dx + dy * dy + dz * dz);
    if (d == 0.0f) d = 0.5f;                       // reference: where(dist==0, 0.5, dist)
    invd[e] = __float2half((1.0f / d) * 0.00390625f);  // prescale 1/256
}

// Pre-shuffle W [KT][FO] (row-major f32) into MFMA B-fragment order:
// Wf[((s*NT + t)*64 + lane)*8 + j] = W[s*32 + (lane>>4)*8 + j][t*16 + (lane&15)]
__global__ __launch_bounds__(256) void shuffle_w_kernel(const float* __restrict__ W,
                                                        __half* __restrict__ Wf,
                                                        int KT, int FO) {
    int e = blockIdx.x * 256 + threadIdx.x;
    if (e >= KT * FO) return;
    int j = e & 7;
    int lane = (e >> 3) & 63;
    int rest = e >> 9;
    int NT = FO >> 4;
    int t = rest % NT;
    int s = rest / NT;
    int k = s * 32 + (lane >> 4) * 8 + j;
    int n = t * 16 + (lane & 15);
    Wf[e] = __float2half(W[k * FO + n]);
}

// ---------------- L0: F_IN=16, F_OUT=128, 128 rows/block ----------------
__global__ __launch_bounds__(256) void layer0_kernel(
    const __half* __restrict__ hprev, const __half* __restrict__ invd,
    const int* __restrict__ nbr, const __half* __restrict__ Wf,
    const float* __restrict__ bias, __half* __restrict__ outp) {
    __shared__ __align__(16) __half Bs[16384];  // 32 KB weights, staged once

    const int tid = threadIdx.x;
    const int wave = tid >> 6;
    const int lane = tid & 63;
    const int quad = lane >> 4;
    const int lmod = lane & 15;
    const int mbase = blockIdx.x * 128 + wave * 16 + lmod;

    int idx[2][8];
    f16x8 invr[2];
#pragma unroll
    for (int mt = 0; mt < 2; ++mt) {
        const int m = mbase + mt * 64;
        const int4* nrow = (const int4*)(nbr + (size_t)m * 8);
        const int4 iA = nrow[0];
        const int4 iB = nrow[1];
        idx[mt][0] = iA.x; idx[mt][1] = iA.y; idx[mt][2] = iA.z; idx[mt][3] = iA.w;
        idx[mt][4] = iB.x; idx[mt][5] = iB.y; idx[mt][6] = iB.z; idx[mt][7] = iB.w;
        invr[mt] = *(const f16x8*)(invd + (size_t)m * 8);
    }

    f32x4 acc[2][8];
#pragma unroll
    for (int mt = 0; mt < 2; ++mt)
#pragma unroll
        for (int t = 0; t < 8; ++t) acc[mt][t] = f32x4{0.f, 0.f, 0.f, 0.f};

    {
        const uint4* src = (const uint4*)Wf;
        uint4* dst = (uint4*)Bs;
#pragma unroll
        for (int i = 0; i < 8; ++i) dst[i * 256 + tid] = src[i * 256 + tid];
    }
    __syncthreads();

#pragma unroll
    for (int s = 0; s < 4; ++s) {
        const int nb = 2 * s + (quad >> 1);
        f16x8 as[2];
#pragma unroll
        for (int mt = 0; mt < 2; ++mt) {
            f16x8 av = *(const f16x8*)(hprev + (size_t)idx[mt][nb] * 16 + (quad & 1) * 8);
            as[mt] = av * invr[mt][nb];
        }
#pragma unroll
        for (int t = 0; t < 8; ++t) {
            f16x8 b = *(const f16x8*)(Bs + ((size_t)(s * 8 + t) * 64 + lane) * 8);
#pragma unroll
            for (int mt = 0; mt < 2; ++mt)
                acc[mt][t] = __builtin_amdgcn_mfma_f32_16x16x32_f16(as[mt], b, acc[mt][t], 0, 0, 0);
        }
    }

#pragma unroll
    for (int mt = 0; mt < 2; ++mt) {
        const int rbase = blockIdx.x * 128 + mt * 64 + wave * 16 + quad * 4;
#pragma unroll
        for (int t = 0; t < 8; ++t) {
            const int col = t * 16 + lmod;
            const float bv = bias[col];
#pragma unroll
            for (int rr = 0; rr < 4; ++rr) {
                float v = acc[mt][t][rr] * 256.0f + bv;
                outp[(size_t)(rbase + rr) * 128 + col] = __float2half(v);
            }
        }
    }
}

// ---------------- L1: F_IN=128, F_OUT=128, 64 rows/block, t-specialized ----
// LDS: seg-major + XOR swizzle, 16B granules: off16(seg,row) =
//   seg*64 + (row & ~15) + ((row ^ seg) & 15)
__device__ __forceinline__ int off16(int seg, int row) {
    return seg * 64 + (row & ~15) + ((row ^ seg) & 15);
}

__global__ __launch_bounds__(256, 3) void layer1_kernel(
    const __half* __restrict__ hprev, const __half* __restrict__ invd,
    const int* __restrict__ nbr, const __half* __restrict__ Wf,
    const float* __restrict__ bias, __half* __restrict__ outp) {
    __shared__ __align__(16) __half As[2][16384];  // 2 x 16 segs x 64 rows x 16B

    const int tid = threadIdx.x;
    const int wave = tid >> 6;
    const int lane = tid & 63;
    const int quad = lane >> 4;
    const int lmod = lane & 15;
    const int rowblk = blockIdx.x * 64;
    const int seg = lmod;  // staging: this thread's 16B segment

    // Staging rows for this wave: 4 insts x 4 rows (quad picks row-in-inst).
    int srow[4], grow_[4], soff[4];
#pragma unroll
    for (int i = 0; i < 4; ++i) {
        srow[i] = wave * 16 + i * 4 + quad;
        grow_[i] = rowblk + srow[i];
        soff[i] = off16(seg, srow[i]) * 8;  // halves
    }

    f16x8 invS[4];
#pragma unroll
    for (int i = 0; i < 4; ++i) invS[i] = *(const f16x8*)(invd + (size_t)grow_[i] * 8);

    // Index pipeline: idxP[(nb+1)&1] holds idx for nb+1 at start of iter nb.
    int idx0[4], idxP[2][4];
#pragma unroll
    for (int i = 0; i < 4; ++i) idx0[i] = nbr[(size_t)grow_[i] * 8 + 0];
#pragma unroll
    for (int i = 0; i < 4; ++i) idxP[1][i] = nbr[(size_t)grow_[i] * 8 + 1];

    // This wave's two output col-tiles: t = wave*2 + tl.
    const __half* WfB = Wf + ((size_t)(wave * 2) * 64 + lane) * 8;

    f16x8 Bc[4][2], Bn[4][2];
#pragma unroll
    for (int ks = 0; ks < 4; ++ks)
#pragma unroll
        for (int tl = 0; tl < 2; ++tl)
            Bc[ks][tl] = *(const f16x8*)(WfB + (size_t)(ks * 8 + tl) * 512);

    // Fragment-read offsets (halves): seg=ks*4+quad, row=m*16+lmod.
    int roff[4][4];
#pragma unroll
    for (int m = 0; m < 4; ++m)
#pragma unroll
        for (int ks = 0; ks < 4; ++ks)
            roff[m][ks] = off16(ks * 4 + quad, m * 16 + lmod) * 8;

    // Stage nb=0.
    f16x8 ga[4];
#pragma unroll
    for (int i = 0; i < 4; ++i)
        ga[i] = *(const f16x8*)(hprev + (size_t)idx0[i] * 128 + seg * 8);
#pragma unroll
    for (int i = 0; i < 4; ++i) {
        f16x8 v = ga[i] * invS[i][0];
        *(f16x8*)(&As[0][soff[i]]) = v;
    }
    __syncthreads();

    f32x4 acc[4][2];
#pragma unroll
    for (int m = 0; m < 4; ++m) { acc[m][0] = f32x4{0.f,0.f,0.f,0.f}; acc[m][1] = f32x4{0.f,0.f,0.f,0.f}; }

#pragma unroll
    for (int nb = 0; nb < 8; ++nb) {
        const int cur = nb & 1;
        // Issue gathers for nb+1 (indices arrived a full iteration ago).
        if (nb < 7) {
#pragma unroll
            for (int i = 0; i < 4; ++i)
                ga[i] = *(const f16x8*)(hprev + (size_t)idxP[(nb + 1) & 1][i] * 128 + seg * 8);
        }
        // Issue index loads for nb+2 into the slot freed by nb.
        if (nb < 6) {
#pragma unroll
            for (int i = 0; i < 4; ++i)
                idxP[nb & 1][i] = nbr[(size_t)grow_[i] * 8 + nb + 2];
        }
        // Issue B-fragment loads for nb+1 (L2-resident stream).
        if (nb < 7) {
#pragma unroll
            for (int ks = 0; ks < 4; ++ks)
#pragma unroll
                for (int tl = 0; tl < 2; ++tl)
                    Bn[ks][tl] = *(const f16x8*)(WfB + (size_t)(((nb + 1) * 4 + ks) * 8 + tl) * 512);
        }
        // Compute nb: 16 ds_read_b128, 32 MFMA (each A frag feeds 2 MFMAs).
#pragma unroll
        for (int m = 0; m < 4; ++m) {
#pragma unroll
            for (int ks = 0; ks < 4; ++ks) {
                f16x8 a = *(const f16x8*)(&As[cur][roff[m][ks]]);
                acc[m][0] = __builtin_amdgcn_mfma_f32_16x16x32_f16(a, Bc[ks][0], acc[m][0], 0, 0, 0);
                acc[m][1] = __builtin_amdgcn_mfma_f32_16x16x32_f16(a, Bc[ks][1], acc[m][1], 0, 0, 0);
            }
        }
        // Stage nb+1 into the other buffer; rotate B; one barrier per nb.
        if (nb < 7) {
#pragma unroll
            for (int i = 0; i < 4; ++i) {
                f16x8 v = ga[i] * invS[i][nb + 1];
                *(f16x8*)(&As[cur ^ 1][soff[i]]) = v;
            }
#pragma unroll
            for (int ks = 0; ks < 4; ++ks) { Bc[ks][0] = Bn[ks][0]; Bc[ks][1] = Bn[ks][1]; }
            __syncthreads();
        }
    }

    // Epilogue: rows 0..63, cols wave*32..+32. LeakyReLU.
#pragma unroll
    for (int m = 0; m < 4; ++m) {
#pragma unroll
        for (int tl = 0; tl < 2; ++tl) {
            const int col = wave * 32 + tl * 16 + lmod;
            const float bv = bias[col];
#pragma unroll
            for (int rr = 0; rr < 4; ++rr) {
                const int grow = rowblk + m * 16 + quad * 4 + rr;
                float v = acc[m][tl][rr] * 256.0f + bv;
                v = (v >= 0.f) ? v : 0.01f * v;
                outp[(size_t)grow * 128 + col] = __float2half(v);
            }
        }
    }
}

// ---------------- L2: F_IN=128, F_OUT=16, 64 rows/block, rolling gather ----
__global__ __launch_bounds__(256) void layer2_kernel(
    const __half* __restrict__ hprev, const __half* __restrict__ invd,
    const int* __restrict__ nbr, const __half* __restrict__ Wf,
    const float* __restrict__ bias, float* __restrict__ outp) {
    __shared__ __align__(16) __half Bs[16384];  // 32 KB weights, staged once

    const int tid = threadIdx.x;
    const int wave = tid >> 6;
    const int lane = tid & 63;
    const int quad = lane >> 4;
    const int lmod = lane & 15;
    const int m = blockIdx.x * 64 + wave * 16 + lmod;

    const int4* nrow = (const int4*)(nbr + (size_t)m * 8);
    const int4 iA = nrow[0];
    const int4 iB = nrow[1];
    const int idx[8] = {iA.x, iA.y, iA.z, iA.w, iB.x, iB.y, iB.z, iB.w};
    const f16x8 invr = *(const f16x8*)(invd + (size_t)m * 8);

    {
        const uint4* src = (const uint4*)Wf;
        uint4* dst = (uint4*)Bs;
#pragma unroll
        for (int i = 0; i < 8; ++i) dst[i * 256 + tid] = src[i * 256 + tid];
    }
    __syncthreads();

    // Rolling 3-deep neighbor prefetch; barrier-free loop.
    f16x8 a[3][4];
#pragma unroll
    for (int d = 0; d < 3; ++d)
#pragma unroll
        for (int ks = 0; ks < 4; ++ks)
            a[d][ks] = *(const f16x8*)(hprev + (size_t)idx[d] * 128 + ks * 32 + quad * 8);

    f32x4 acc = f32x4{0.f, 0.f, 0.f, 0.f};
#pragma unroll
    for (int nb = 0; nb < 8; ++nb) {
        const int slot = nb % 3;
#pragma unroll
        for (int ks = 0; ks < 4; ++ks) {
            f16x8 as = a[slot][ks] * invr[nb];
            f16x8 b = *(const f16x8*)(Bs + ((size_t)(nb * 4 + ks) * 64 + lane) * 8);
            acc = __builtin_amdgcn_mfma_f32_16x16x32_f16(as, b, acc, 0, 0, 0);
        }
        if (nb < 5) {
#pragma unroll
            for (int ks = 0; ks < 4; ++ks)
                a[slot][ks] = *(const f16x8*)(hprev + (size_t)idx[nb + 3] * 128 + ks * 32 + quad * 8);
        }
    }

    const int rbase = blockIdx.x * 64 + wave * 16 + quad * 4;
    const float bv = bias[lmod];
#pragma unroll
    for (int rr = 0; rr < 4; ++rr)
        outp[(size_t)(rbase + rr) * 16 + lmod] = acc[rr] * 256.0f + bv;
}

extern "C" void kernel_launch(void* const* d_in, const int* in_sizes, int n_in,
                              void* d_out, int out_size, void* d_ws, size_t ws_size,
                              hipStream_t stream) {
    const float* h   = (const float*)d_in[0];
    const float* pos = (const float*)d_in[1];
    const int*   nbr = (const int*)d_in[2];
    const float* W0  = (const float*)d_in[3];
    const float* b0  = (const float*)d_in[4];
    const float* W1  = (const float*)d_in[5];
    const float* b1  = (const float*)d_in[6];
    const float* W2  = (const float*)d_in[7];
    const float* b2  = (const float*)d_in[8];

    const int N = NNODES;

    // ws: ONLY the two 64 MiB fp16 intermediates (128 MiB total).
    char* w = (char*)d_ws;
    __half* h1 = (__half*)w;                               // 67,108,864 B
    __half* h2 = (__half*)(w + (size_t)67108864);          // 67,108,864 B
    // layer-2 copies of invd/Wf2, placed in the dead h1 region:
    __half* invd2 = (__half*)w;                            // 4,194,304 B
    __half* W2f2  = (__half*)(w + (size_t)4194304);        // 32,768 B

    // d_out doubles as scratch until layer 2 overwrites all of it (16 MiB).
    char* ob = (char*)d_out;
    __half* invd = (__half*)(ob + 0);                      // 4,194,304 B
    __half* h16  = (__half*)(ob + 4194304);                // 8,388,608 B
    __half* W0f  = (__half*)(ob + 12582912);               // 32,768 B
    __half* W1f  = (__half*)(ob + 12615680);               // 262,144 B
    __half* W2f  = (__half*)(ob + 12877824);               // 32,768 B  (end 12,910,592 <= 16,777,216)

    conv_h_kernel<<<(N * 16 + 255) / 256, 256, 0, stream>>>(h, h16, N * 16);
    prep_edges_kernel<<<(N * 8 + 255) / 256, 256, 0, stream>>>(pos, nbr, invd, N * 8);
    shuffle_w_kernel<<<(128 * 128 + 255) / 256, 256, 0, stream>>>(W0, W0f, 128, 128);
    shuffle_w_kernel<<<(1024 * 128 + 255) / 256, 256, 0, stream>>>(W1, W1f, 1024, 128);
    shuffle_w_kernel<<<(1024 * 16 + 255) / 256, 256, 0, stream>>>(W2, W2f, 1024, 16);

    layer0_kernel<<<N / 128, 256, 0, stream>>>(h16, invd, nbr, W0f, b0, h1);
    layer1_kernel<<<N / 64, 256, 0, stream>>>(h1, invd, nbr, W1f, b1, h2);

    // Move what layer 2 needs out of d_out (h1 is dead now).
    (void)hipMemcpyAsync(invd2, invd, 4194304, hipMemcpyDeviceToDevice, stream);
    (void)hipMemcpyAsync(W2f2, W2f, 32768, hipMemcpyDeviceToDevice, stream);

    layer2_kernel<<<N / 64, 256, 0, stream>>>(h2, invd2, nbr, W2f2, b2, (float*)d_out);
}

// Round 10
// 332.985 us; speedup vs baseline: 1.0093x; 1.0093x over previous
//
#include <hip/hip_runtime.h>
#include <hip/hip_fp16.h>

// 3-layer gather-GEMM GNN (N=262144, K=8, 16->128->128->16), f16 MFMA.
// Round 10: fix round-9's LDS over-allocation. The swizzled space
//   off16(seg,row) = seg*64 + (row&~15) + ((row^seg)&15)  (16B granules)
// spans exactly 1024 granules = 8192 halves per buffer; round 9 declared
// As[2][16384] (64 KB) by mistake -> 2 blocks/CU. Now As[2][8192] (32 KB)
// -> 5 blocks/CU, 2.5x gather concurrency. Conflicts verified 0 in round 9.
// L0/L2 unchanged. Scaled messages prescaled by 2^-8; epilogue x256 + bias.
//
// Workspace: ws holds ONLY h1+h2 (128 MiB exactly). invd/h16/shuffled-W live
// in d_out (scratch until layer 2 overwrites it); layer 2's invd+Wf2 are
// d2d-copied into the dead h1 region first.

typedef _Float16 f16x8 __attribute__((ext_vector_type(8)));
typedef float f32x4 __attribute__((ext_vector_type(4)));

#define NNODES 262144

__global__ __launch_bounds__(256) void conv_h_kernel(const float* __restrict__ h,
                                                     __half* __restrict__ h16, int n) {
    int i = blockIdx.x * 256 + threadIdx.x;
    if (i < n) h16[i] = __float2half(h[i]);
}

__global__ __launch_bounds__(256) void prep_edges_kernel(const float* __restrict__ pos,
                                                         const int* __restrict__ nbr,
                                                         __half* __restrict__ invd, int n_edges) {
    int e = blockIdx.x * 256 + threadIdx.x;
    if (e >= n_edges) return;
    int i = e >> 3;
    int n = nbr[e];
    float dx = pos[i * 3 + 0] - pos[n * 3 + 0];
    float dy = pos[i * 3 + 1] - pos[n * 3 + 1];
    float dz = pos[i * 3 + 2] - pos[n * 3 + 2];
    float d = sqrtf(dx * dx + dy * dy + dz * dz);
    if (d == 0.0f) d = 0.5f;                       // reference: where(dist==0, 0.5, dist)
    invd[e] = __float2half((1.0f / d) * 0.00390625f);  // prescale 1/256
}

// Pre-shuffle W [KT][FO] (row-major f32) into MFMA B-fragment order:
// Wf[((s*NT + t)*64 + lane)*8 + j] = W[s*32 + (lane>>4)*8 + j][t*16 + (lane&15)]
__global__ __launch_bounds__(256) void shuffle_w_kernel(const float* __restrict__ W,
                                                        __half* __restrict__ Wf,
                                                        int KT, int FO) {
    int e = blockIdx.x * 256 + threadIdx.x;
    if (e >= KT * FO) return;
    int j = e & 7;
    int lane = (e >> 3) & 63;
    int rest = e >> 9;
    int NT = FO >> 4;
    int t = rest % NT;
    int s = rest / NT;
    int k = s * 32 + (lane >> 4) * 8 + j;
    int n = t * 16 + (lane & 15);
    Wf[e] = __float2half(W[k * FO + n]);
}

// ---------------- L0: F_IN=16, F_OUT=128, 128 rows/block ----------------
__global__ __launch_bounds__(256) void layer0_kernel(
    const __half* __restrict__ hprev, const __half* __restrict__ invd,
    const int* __restrict__ nbr, const __half* __restrict__ Wf,
    const float* __restrict__ bias, __half* __restrict__ outp) {
    __shared__ __align__(16) __half Bs[16384];  // 32 KB weights, staged once

    const int tid = threadIdx.x;
    const int wave = tid >> 6;
    const int lane = tid & 63;
    const int quad = lane >> 4;
    const int lmod = lane & 15;
    const int mbase = blockIdx.x * 128 + wave * 16 + lmod;

    int idx[2][8];
    f16x8 invr[2];
#pragma unroll
    for (int mt = 0; mt < 2; ++mt) {
        const int m = mbase + mt * 64;
        const int4* nrow = (const int4*)(nbr + (size_t)m * 8);
        const int4 iA = nrow[0];
        const int4 iB = nrow[1];
        idx[mt][0] = iA.x; idx[mt][1] = iA.y; idx[mt][2] = iA.z; idx[mt][3] = iA.w;
        idx[mt][4] = iB.x; idx[mt][5] = iB.y; idx[mt][6] = iB.z; idx[mt][7] = iB.w;
        invr[mt] = *(const f16x8*)(invd + (size_t)m * 8);
    }

    f32x4 acc[2][8];
#pragma unroll
    for (int mt = 0; mt < 2; ++mt)
#pragma unroll
        for (int t = 0; t < 8; ++t) acc[mt][t] = f32x4{0.f, 0.f, 0.f, 0.f};

    {
        const uint4* src = (const uint4*)Wf;
        uint4* dst = (uint4*)Bs;
#pragma unroll
        for (int i = 0; i < 8; ++i) dst[i * 256 + tid] = src[i * 256 + tid];
    }
    __syncthreads();

#pragma unroll
    for (int s = 0; s < 4; ++s) {
        const int nb = 2 * s + (quad >> 1);
        f16x8 as[2];
#pragma unroll
        for (int mt = 0; mt < 2; ++mt) {
            f16x8 av = *(const f16x8*)(hprev + (size_t)idx[mt][nb] * 16 + (quad & 1) * 8);
            as[mt] = av * invr[mt][nb];
        }
#pragma unroll
        for (int t = 0; t < 8; ++t) {
            f16x8 b = *(const f16x8*)(Bs + ((size_t)(s * 8 + t) * 64 + lane) * 8);
#pragma unroll
            for (int mt = 0; mt < 2; ++mt)
                acc[mt][t] = __builtin_amdgcn_mfma_f32_16x16x32_f16(as[mt], b, acc[mt][t], 0, 0, 0);
        }
    }

#pragma unroll
    for (int mt = 0; mt < 2; ++mt) {
        const int rbase = blockIdx.x * 128 + mt * 64 + wave * 16 + quad * 4;
#pragma unroll
        for (int t = 0; t < 8; ++t) {
            const int col = t * 16 + lmod;
            const float bv = bias[col];
#pragma unroll
            for (int rr = 0; rr < 4; ++rr) {
                float v = acc[mt][t][rr] * 256.0f + bv;
                outp[(size_t)(rbase + rr) * 128 + col] = __float2half(v);
            }
        }
    }
}

// ---------------- L1: F_IN=128, F_OUT=128, 64 rows/block, t-specialized ----
// LDS: seg-major + XOR swizzle, 16B granules: off16(seg,row) =
//   seg*64 + (row & ~15) + ((row ^ seg) & 15)   -> spans [0, 1024) granules.
__device__ __forceinline__ int off16(int seg, int row) {
    return seg * 64 + (row & ~15) + ((row ^ seg) & 15);
}

__global__ __launch_bounds__(256, 3) void layer1_kernel(
    const __half* __restrict__ hprev, const __half* __restrict__ invd,
    const int* __restrict__ nbr, const __half* __restrict__ Wf,
    const float* __restrict__ bias, __half* __restrict__ outp) {
    __shared__ __align__(16) __half As[2][8192];  // 2 x 1024 granules x 16B = 32 KB

    const int tid = threadIdx.x;
    const int wave = tid >> 6;
    const int lane = tid & 63;
    const int quad = lane >> 4;
    const int lmod = lane & 15;
    const int rowblk = blockIdx.x * 64;
    const int seg = lmod;  // staging: this thread's 16B segment

    // Staging rows for this wave: 4 insts x 4 rows (quad picks row-in-inst).
    int srow[4], grow_[4], soff[4];
#pragma unroll
    for (int i = 0; i < 4; ++i) {
        srow[i] = wave * 16 + i * 4 + quad;
        grow_[i] = rowblk + srow[i];
        soff[i] = off16(seg, srow[i]) * 8;  // halves
    }

    f16x8 invS[4];
#pragma unroll
    for (int i = 0; i < 4; ++i) invS[i] = *(const f16x8*)(invd + (size_t)grow_[i] * 8);

    // Index pipeline: idxP[(nb+1)&1] holds idx for nb+1 at start of iter nb.
    int idx0[4], idxP[2][4];
#pragma unroll
    for (int i = 0; i < 4; ++i) idx0[i] = nbr[(size_t)grow_[i] * 8 + 0];
#pragma unroll
    for (int i = 0; i < 4; ++i) idxP[1][i] = nbr[(size_t)grow_[i] * 8 + 1];

    // This wave's two output col-tiles: t = wave*2 + tl.
    const __half* WfB = Wf + ((size_t)(wave * 2) * 64 + lane) * 8;

    f16x8 Bc[4][2], Bn[4][2];
#pragma unroll
    for (int ks = 0; ks < 4; ++ks)
#pragma unroll
        for (int tl = 0; tl < 2; ++tl)
            Bc[ks][tl] = *(const f16x8*)(WfB + (size_t)(ks * 8 + tl) * 512);

    // Fragment-read offsets (halves): seg=ks*4+quad, row=m*16+lmod.
    int roff[4][4];
#pragma unroll
    for (int m = 0; m < 4; ++m)
#pragma unroll
        for (int ks = 0; ks < 4; ++ks)
            roff[m][ks] = off16(ks * 4 + quad, m * 16 + lmod) * 8;

    // Stage nb=0.
    f16x8 ga[4];
#pragma unroll
    for (int i = 0; i < 4; ++i)
        ga[i] = *(const f16x8*)(hprev + (size_t)idx0[i] * 128 + seg * 8);
#pragma unroll
    for (int i = 0; i < 4; ++i) {
        f16x8 v = ga[i] * invS[i][0];
        *(f16x8*)(&As[0][soff[i]]) = v;
    }
    __syncthreads();

    f32x4 acc[4][2];
#pragma unroll
    for (int m = 0; m < 4; ++m) { acc[m][0] = f32x4{0.f,0.f,0.f,0.f}; acc[m][1] = f32x4{0.f,0.f,0.f,0.f}; }

#pragma unroll
    for (int nb = 0; nb < 8; ++nb) {
        const int cur = nb & 1;
        // Issue gathers for nb+1 (indices arrived a full iteration ago).
        if (nb < 7) {
#pragma unroll
            for (int i = 0; i < 4; ++i)
                ga[i] = *(const f16x8*)(hprev + (size_t)idxP[(nb + 1) & 1][i] * 128 + seg * 8);
        }
        // Issue index loads for nb+2 into the slot freed by nb.
        if (nb < 6) {
#pragma unroll
            for (int i = 0; i < 4; ++i)
                idxP[nb & 1][i] = nbr[(size_t)grow_[i] * 8 + nb + 2];
        }
        // Issue B-fragment loads for nb+1 (L2-resident stream).
        if (nb < 7) {
#pragma unroll
            for (int ks = 0; ks < 4; ++ks)
#pragma unroll
                for (int tl = 0; tl < 2; ++tl)
                    Bn[ks][tl] = *(const f16x8*)(WfB + (size_t)(((nb + 1) * 4 + ks) * 8 + tl) * 512);
        }
        // Compute nb: 16 ds_read_b128, 32 MFMA (each A frag feeds 2 MFMAs).
#pragma unroll
        for (int m = 0; m < 4; ++m) {
#pragma unroll
            for (int ks = 0; ks < 4; ++ks) {
                f16x8 a = *(const f16x8*)(&As[cur][roff[m][ks]]);
                acc[m][0] = __builtin_amdgcn_mfma_f32_16x16x32_f16(a, Bc[ks][0], acc[m][0], 0, 0, 0);
                acc[m][1] = __builtin_amdgcn_mfma_f32_16x16x32_f16(a, Bc[ks][1], acc[m][1], 0, 0, 0);
            }
        }
        // Stage nb+1 into the other buffer; rotate B; one barrier per nb.
        if (nb < 7) {
#pragma unroll
            for (int i = 0; i < 4; ++i) {
                f16x8 v = ga[i] * invS[i][nb + 1];
                *(f16x8*)(&As[cur ^ 1][soff[i]]) = v;
            }
#pragma unroll
            for (int ks = 0; ks < 4; ++ks) { Bc[ks][0] = Bn[ks][0]; Bc[ks][1] = Bn[ks][1]; }
            __syncthreads();
        }
    }

    // Epilogue: rows 0..63, cols wave*32..+32. LeakyReLU.
#pragma unroll
    for (int m = 0; m < 4; ++m) {
#pragma unroll
        for (int tl = 0; tl < 2; ++tl) {
            const int col = wave * 32 + tl * 16 + lmod;
            const float bv = bias[col];
#pragma unroll
            for (int rr = 0; rr < 4; ++rr) {
                const int grow = rowblk + m * 16 + quad * 4 + rr;
                float v = acc[m][tl][rr] * 256.0f + bv;
                v = (v >= 0.f) ? v : 0.01f * v;
                outp[(size_t)grow * 128 + col] = __float2half(v);
            }
        }
    }
}

// ---------------- L2: F_IN=128, F_OUT=16, 64 rows/block, rolling gather ----
__global__ __launch_bounds__(256) void layer2_kernel(
    const __half* __restrict__ hprev, const __half* __restrict__ invd,
    const int* __restrict__ nbr, const __half* __restrict__ Wf,
    const float* __restrict__ bias, float* __restrict__ outp) {
    __shared__ __align__(16) __half Bs[16384];  // 32 KB weights, staged once

    const int tid = threadIdx.x;
    const int wave = tid >> 6;
    const int lane = tid & 63;
    const int quad = lane >> 4;
    const int lmod = lane & 15;
    const int m = blockIdx.x * 64 + wave * 16 + lmod;

    const int4* nrow = (const int4*)(nbr + (size_t)m * 8);
    const int4 iA = nrow[0];
    const int4 iB = nrow[1];
    const int idx[8] = {iA.x, iA.y, iA.z, iA.w, iB.x, iB.y, iB.z, iB.w};
    const f16x8 invr = *(const f16x8*)(invd + (size_t)m * 8);

    {
        const uint4* src = (const uint4*)Wf;
        uint4* dst = (uint4*)Bs;
#pragma unroll
        for (int i = 0; i < 8; ++i) dst[i * 256 + tid] = src[i * 256 + tid];
    }
    __syncthreads();

    // Rolling 3-deep neighbor prefetch; barrier-free loop.
    f16x8 a[3][4];
#pragma unroll
    for (int d = 0; d < 3; ++d)
#pragma unroll
        for (int ks = 0; ks < 4; ++ks)
            a[d][ks] = *(const f16x8*)(hprev + (size_t)idx[d] * 128 + ks * 32 + quad * 8);

    f32x4 acc = f32x4{0.f, 0.f, 0.f, 0.f};
#pragma unroll
    for (int nb = 0; nb < 8; ++nb) {
        const int slot = nb % 3;
#pragma unroll
        for (int ks = 0; ks < 4; ++ks) {
            f16x8 as = a[slot][ks] * invr[nb];
            f16x8 b = *(const f16x8*)(Bs + ((size_t)(nb * 4 + ks) * 64 + lane) * 8);
            acc = __builtin_amdgcn_mfma_f32_16x16x32_f16(as, b, acc, 0, 0, 0);
        }
        if (nb < 5) {
#pragma unroll
            for (int ks = 0; ks < 4; ++ks)
                a[slot][ks] = *(const f16x8*)(hprev + (size_t)idx[nb + 3] * 128 + ks * 32 + quad * 8);
        }
    }

    const int rbase = blockIdx.x * 64 + wave * 16 + quad * 4;
    const float bv = bias[lmod];
#pragma unroll
    for (int rr = 0; rr < 4; ++rr)
        outp[(size_t)(rbase + rr) * 16 + lmod] = acc[rr] * 256.0f + bv;
}

extern "C" void kernel_launch(void* const* d_in, const int* in_sizes, int n_in,
                              void* d_out, int out_size, void* d_ws, size_t ws_size,
                              hipStream_t stream) {
    const float* h   = (const float*)d_in[0];
    const float* pos = (const float*)d_in[1];
    const int*   nbr = (const int*)d_in[2];
    const float* W0  = (const float*)d_in[3];
    const float* b0  = (const float*)d_in[4];
    const float* W1  = (const float*)d_in[5];
    const float* b1  = (const float*)d_in[6];
    const float* W2  = (const float*)d_in[7];
    const float* b2  = (const float*)d_in[8];

    const int N = NNODES;

    // ws: ONLY the two 64 MiB fp16 intermediates (128 MiB total).
    char* w = (char*)d_ws;
    __half* h1 = (__half*)w;                               // 67,108,864 B
    __half* h2 = (__half*)(w + (size_t)67108864);          // 67,108,864 B
    // layer-2 copies of invd/Wf2, placed in the dead h1 region:
    __half* invd2 = (__half*)w;                            // 4,194,304 B
    __half* W2f2  = (__half*)(w + (size_t)4194304);        // 32,768 B

    // d_out doubles as scratch until layer 2 overwrites all of it (16 MiB).
    char* ob = (char*)d_out;
    __half* invd = (__half*)(ob + 0);                      // 4,194,304 B
    __half* h16  = (__half*)(ob + 4194304);                // 8,388,608 B
    __half* W0f  = (__half*)(ob + 12582912);               // 32,768 B
    __half* W1f  = (__half*)(ob + 12615680);               // 262,144 B
    __half* W2f  = (__half*)(ob + 12877824);               // 32,768 B  (end 12,910,592 <= 16,777,216)

    conv_h_kernel<<<(N * 16 + 255) / 256, 256, 0, stream>>>(h, h16, N * 16);
    prep_edges_kernel<<<(N * 8 + 255) / 256, 256, 0, stream>>>(pos, nbr, invd, N * 8);
    shuffle_w_kernel<<<(128 * 128 + 255) / 256, 256, 0, stream>>>(W0, W0f, 128, 128);
    shuffle_w_kernel<<<(1024 * 128 + 255) / 256, 256, 0, stream>>>(W1, W1f, 1024, 128);
    shuffle_w_kernel<<<(1024 * 16 + 255) / 256, 256, 0, stream>>>(W2, W2f, 1024, 16);

    layer0_kernel<<<N / 128, 256, 0, stream>>>(h16, invd, nbr, W0f, b0, h1);
    layer1_kernel<<<N / 64, 256, 0, stream>>>(h1, invd, nbr, W1f, b1, h2);

    // Move what layer 2 needs out of d_out (h1 is dead now).
    (void)hipMemcpyAsync(invd2, invd, 4194304, hipMemcpyDeviceToDevice, stream);
    (void)hipMemcpyAsync(W2f2, W2f, 32768, hipMemcpyDeviceToDevice, stream);

    layer2_kernel<<<N / 64, 256, 0, stream>>>(h2, invd2, nbr, W2f2, b2, (float*)d_out);
}